// Round 6
// baseline (81.145 us; speedup 1.0000x reference)
//
#include <hip/hip_runtime.h>

// ---- compile-time physics constants (computed in double, cast to float) ----
constexpr double PI_D         = 3.14159265358979323846;
constexpr double WAVELENGTH_D = 12.398 / 11.3;
constexpr double K_D          = 2.0 * PI_D / WAVELENGTH_D;
constexpr double PIXELSIZE_D  = 5.5e-05 * 2.0;
constexpr double DISTANCE_D   = 0.85;
constexpr double WX_D         = K_D * PIXELSIZE_D / DISTANCE_D / 10.0;   // == WY
constexpr float  INVW2        = (float)(1.0 / (WX_D * WX_D));
constexpr float  TWO_PI_C_L   = (float)(2.0 * PI_D / 4.013 * 2.0);
constexpr float  DEG2RAD      = (float)(PI_D / 180.0);
constexpr float  GYCUT        = 88.0f;    // exp(-88) ~ 6e-39: negligible

constexpr int DET    = 4096;   // 64*64 detector pixels
constexpr int NCHUNK = 32;     // point-level mod-32 interleave of the O-sum

__global__ __launch_bounds__(256) void img_gen_kernel(
    const float* __restrict__ params,
    const float* __restrict__ dQx,
    const float* __restrict__ dQy,
    const float* __restrict__ dQz,
    const float* __restrict__ oQx,
    const float* __restrict__ oQy,
    const float* __restrict__ oQz,
    float* __restrict__ out,
    int N)
{
    const int tidg = blockIdx.x * 256 + threadIdx.x;  // 0..16383 = b*4096 + pix
    const int b    = tidg >> 12;
    const int pix  = tidg & (DET - 1);
    const int lane = threadIdx.x & 63;                // wave = one detector row
    const int c    = blockIdx.y;                      // chunk: points n == c (mod 32)

    const float thickness = params[b * 4 + 0];
    const float strain    = params[b * 4 + 1];
    const float tilt_lr   = params[b * 4 + 2] * DEG2RAD;
    const float tilt_ud   = params[b * 4 + 3] * DEG2RAD;
    const float shift     = TWO_PI_C_L / (1.0f + strain);

    const float dx    = dQx[pix] + shift * tilt_lr;   // per-lane (column)
    const float dy    = dQy[pix] + shift * tilt_ud;   // wave-uniform (row)
    const float dz    = dQz[pix] - shift;             // per-lane (column)
    const float halfT = 0.5f * thickness;

    // chunk c, lane l, group j -> point n = c + NCHUNK*(64*j + l).
    // Point-level interleave: a row's ~200-point contiguous hit band spreads
    // ~6 hits to EVERY chunk (group-level interleave left 64-hit long poles).
    constexpr int STEP = NCHUNK * 64;                 // 2048 points per group
    const int ngroups  = (N + STEP - 1) / STEP;       // ~4 for N~6.5k

    float acc = 0.0f;

    // depth-1 software pipeline over groups
    int   idx = c + NCHUNK * lane;
    int   ns  = min(idx, N - 1);
    float yv = oQy[ns], xv = oQx[ns], zv = oQz[ns];
    bool  va = (idx < N);

    for (int j = 0;;) {
        const bool have_next = (j + 1 < ngroups);     // block-uniform
        float yn, xn, zn; bool vn = false;
        if (have_next) {                              // issue next loads early
            const int n2  = idx + STEP;
            const int n2s = min(n2, N - 1);
            yn = oQy[n2s]; xn = oQx[n2s]; zn = oQz[n2s];
            vn = (n2 < N);
        }

        // 64-wide y-test (dy wave-uniform -> mask identical across lanes)
        const float qys = dy - yv;
        const float gys = va ? qys * qys * INVW2 : 1e30f;
        unsigned long long mask = __ballot(gys < GYCUT);

        // wave-uniform loop over hit points; operands via shfl (no loads)
        while (mask) {
            const int i = __ffsll((long long)mask) - 1;
            mask &= mask - 1;
            const float yb = __shfl(yv, i);
            const float xb = __shfl(xv, i);
            const float zb = __shfl(zv, i);
            const float qy = dy - yb;                 // uniform
            const float qx = dx - xb;                 // per-lane
            const float qz = dz - zb;                 // per-lane
            const float arg   = halfT * qz;           // = pi * (t*qz/pi/2)
            const float sa    = __sinf(arg);
            const float sincv = (arg != 0.0f) ? __fdividef(sa, arg) : 1.0f;
            const float tf    = thickness * sincv * sincv;
            acc += tf * __expf(-(qx * qx * INVW2 + qy * qy * INVW2));
        }

        if (!have_next) break;
        ++j; idx += STEP; yv = yn; xv = xn; zv = zn; va = vn;
    }

    if (acc != 0.0f) atomicAdd(&out[tidg], acc);
}

extern "C" void kernel_launch(void* const* d_in, const int* in_sizes, int n_in,
                              void* d_out, int out_size, void* d_ws, size_t ws_size,
                              hipStream_t stream) {
    const float* params = (const float*)d_in[0];
    const float* dQx    = (const float*)d_in[1];
    const float* dQy    = (const float*)d_in[2];
    const float* dQz    = (const float*)d_in[3];
    const float* oQx    = (const float*)d_in[4];
    const float* oQy    = (const float*)d_in[5];
    const float* oQz    = (const float*)d_in[6];
    float*       out    = (float*)d_out;
    const int    N      = in_sizes[4];

    // d_out is re-poisoned to 0xAA before every timed launch; zero it first.
    hipMemsetAsync(d_out, 0, (size_t)out_size * sizeof(float), stream);

    dim3 grid((4 * DET) / 256, NCHUNK);   // 64 x 32 blocks, 256 thr -> 32 waves/CU
    img_gen_kernel<<<grid, 256, 0, stream>>>(params, dQx, dQy, dQz,
                                             oQx, oQy, oQz, out, N);
}

// Round 7
// 72.256 us; speedup vs baseline: 1.1230x; 1.1230x over previous
//
#include <hip/hip_runtime.h>
#include <math.h>

// ---- compile-time physics constants (computed in double, cast to float) ----
constexpr double PI_D         = 3.14159265358979323846;
constexpr double WAVELENGTH_D = 12.398 / 11.3;
constexpr double K_D          = 2.0 * PI_D / WAVELENGTH_D;
constexpr double PIXELSIZE_D  = 5.5e-05 * 2.0;
constexpr double DISTANCE_D   = 0.85;
constexpr double WX_D         = K_D * PIXELSIZE_D / DISTANCE_D / 10.0;   // == WY
constexpr float  INVW2        = (float)(1.0 / (WX_D * WX_D));
constexpr float  TWO_PI_C_L   = (float)(2.0 * PI_D / 4.013 * 2.0);
constexpr float  DEG2RAD      = (float)(PI_D / 180.0);

constexpr int DET    = 4096;   // 64*64 detector pixels
constexpr int NCHUNK = 8;      // contiguous split of each row's hit band

// oQy is SORTED ascending (donut mask flattened row-major; O_Qy depends only
// on the O-grid row). The y-band |dy - oQy| < QCUT is a contiguous [lo,hi).

__global__ __launch_bounds__(256) void img_gen_kernel(
    const float* __restrict__ params,
    const float* __restrict__ dQx,
    const float* __restrict__ dQy,
    const float* __restrict__ dQz,
    const float* __restrict__ oQx,
    const float* __restrict__ oQy,
    const float* __restrict__ oQz,
    float* __restrict__ out,
    int N)
{
    const int tidg = blockIdx.x * 256 + threadIdx.x;  // 0..16383 = b*4096 + pix
    const int b    = tidg >> 12;
    const int pix  = tidg & (DET - 1);
    const int lane = threadIdx.x & 63;                // wave = one detector row
    const int c    = blockIdx.y;                      // band slice index

    const float thickness = params[b * 4 + 0];
    const float strain    = params[b * 4 + 1];
    const float tilt_lr   = params[b * 4 + 2] * DEG2RAD;
    const float tilt_ud   = params[b * 4 + 3] * DEG2RAD;
    const float shift     = TWO_PI_C_L / (1.0f + strain);

    const float dx    = dQx[pix] + shift * tilt_lr;   // per-lane (column)
    const float dy    = dQy[pix] + shift * tilt_ud;   // wave-uniform (row)
    const float dz    = dQz[pix] - shift;             // per-lane (column)
    const float halfT = 0.5f * thickness;

    // |qy| < QCUT  <=>  gy = qy^2*INVW2 < 88  (exp(-88) ~ 6e-39: negligible)
    const float QCUT = sqrtf(88.0f) * (float)WX_D;

    // ---- dual wave-parallel 32-ary lower_bound on sorted oQy ----
    // lanes 0-31: first n with oQy[n] >= dy-QCUT   -> lo
    // lanes 32-63: first n with oQy[n] >= dy+QCUT  -> hi
    const int   half   = lane >> 5;
    const int   sl     = lane & 31;
    const float target = dy + (half ? QCUT : -QCUT);
    int a = 0, bnd = N;                               // invariant: a <= ans <= bnd
    while (__any(bnd - a > 32)) {
        const int span = bnd - a;
        const int p    = a + (int)(((long long)span * (sl + 1)) / 33); // in [a,bnd)
        const float v  = oQy[min(p, N - 1)];
        const bool pred = (span > 0) && (v < target);
        const unsigned long long m = __ballot(pred);
        const unsigned k = half ? (unsigned)__popcll(m >> 32)
                                : (unsigned)__popcll(m & 0xffffffffull);
        const int anew = (k > 0)  ? a + (int)(((long long)span * k) / 33) + 1 : a;
        const int bnew = (k < 32) ? a + (int)(((long long)span * (k + 1)) / 33) : bnd;
        a = anew; bnd = bnew;
    }
    {   // final: probe all of [a, bnd), width <= 32
        const int  pos   = a + sl;
        const bool valid = pos < bnd;
        const float v    = oQy[min(pos, N - 1)];
        const bool pred  = valid && (v < target);
        const unsigned long long m = __ballot(pred);
        const unsigned k = half ? (unsigned)__popcll(m >> 32)
                                : (unsigned)__popcll(m & 0xffffffffull);
        a += (int)k;
    }
    const int lo = __shfl(a, 0);
    const int hi = __shfl(a, 32);

    // ---- equal contiguous slice of the band for this chunk ----
    float acc = 0.0f;
    const int len = hi - lo;
    if (len > 0) {
        const int s = lo + (int)((long long)len * c       / NCHUNK);
        const int e = lo + (int)((long long)len * (c + 1) / NCHUNK);
        for (int base = s; base < e; base += 64) {
            const int nn = min(base + lane, N - 1);   // coalesced 64-wide load
            const float yv = oQy[nn];
            const float xv = oQx[nn];
            const float zv = oQz[nn];
            const int cnt = min(64, e - base);
            for (int k2 = 0; k2 < cnt; ++k2) {
                const float yb = __shfl(yv, k2);
                const float xb = __shfl(xv, k2);
                const float zb = __shfl(zv, k2);
                const float qy = dy - yb;             // uniform
                const float qx = dx - xb;             // per-lane
                const float qz = dz - zb;             // per-lane
                const float arg   = halfT * qz;       // = pi * (t*qz/pi/2)
                const float sa    = __sinf(arg);
                const float sincv = (arg != 0.0f) ? __fdividef(sa, arg) : 1.0f;
                const float tf    = thickness * sincv * sincv;
                acc += tf * __expf(-(qx * qx + qy * qy) * INVW2);
            }
        }
    }
    if (acc != 0.0f) atomicAdd(&out[tidg], acc);
}

extern "C" void kernel_launch(void* const* d_in, const int* in_sizes, int n_in,
                              void* d_out, int out_size, void* d_ws, size_t ws_size,
                              hipStream_t stream) {
    const float* params = (const float*)d_in[0];
    const float* dQx    = (const float*)d_in[1];
    const float* dQy    = (const float*)d_in[2];
    const float* dQz    = (const float*)d_in[3];
    const float* oQx    = (const float*)d_in[4];
    const float* oQy    = (const float*)d_in[5];
    const float* oQz    = (const float*)d_in[6];
    float*       out    = (float*)d_out;
    const int    N      = in_sizes[4];

    // d_out is re-poisoned to 0xAA before every timed launch; zero it first.
    hipMemsetAsync(d_out, 0, (size_t)out_size * sizeof(float), stream);

    dim3 grid((4 * DET) / 256, NCHUNK);   // 64 x 8 blocks, 256 thr
    img_gen_kernel<<<grid, 256, 0, stream>>>(params, dQx, dQy, dQz,
                                             oQx, oQy, oQz, out, N);
}